// Round 7
// baseline (11226.349 us; speedup 1.0000x reference)
//
#include <hip/hip_runtime.h>
#include <hip/hip_fp16.h>

#define N_NODES 100000
#define E_EDGES 3200000
#define IN_F 128
#define HID 32
#define PROP 8

#define WIN 16384          // hist window (64 KB LDS)
#define NWIN 7
#define HS 16

#define MB_ROWS 64
#define MB_BLOCKS ((N_NODES + MB_ROWS - 1) / MB_ROWS)   // 1563

// ---- binning geometry ----
#define FB 512             // fill blocks; CH edges each
#define CH 12500           // 2E / FB
#define BK_SH 7
#define BK_N 128           // nodes per bucket
#define NBK 782            // ceil(N / 128)
#define L2S (NBK * FB)     // 400384 = 391*1024 exactly
#define SCB2 391

// ---------- windowed degree histogram ----------
__global__ __launch_bounds__(256) void hist_kernel(const int* __restrict__ s, const int* __restrict__ d,
        const int* __restrict__ ns, const int* __restrict__ nd, int* __restrict__ degs) {
    __shared__ int lh[WIN];
    int b = blockIdx.x;
    int w = b % NWIN;
    int st = (b / NWIN) % 4;
    int sl = b / (NWIN * 4);
    const int* p = (st == 0) ? s : (st == 1) ? d : (st == 2) ? ns : nd;
    for (int i = threadIdx.x; i < WIN; i += 256) lh[i] = 0;
    __syncthreads();
    const int lo = w * WIN;
    const int per = E_EDGES / HS;
    const int4* p4 = (const int4*)(p + sl * per);
    for (int i = threadIdx.x; i < per / 4; i += 256) {
        int4 v = p4[i];
        int a;
        a = v.x - lo; if ((unsigned)a < WIN) atomicAdd(&lh[a], 1);
        a = v.y - lo; if ((unsigned)a < WIN) atomicAdd(&lh[a], 1);
        a = v.z - lo; if ((unsigned)a < WIN) atomicAdd(&lh[a], 1);
        a = v.w - lo; if ((unsigned)a < WIN) atomicAdd(&lh[a], 1);
    }
    __syncthreads();
    int* g = degs + st * N_NODES;
    for (int i = threadIdx.x; i < WIN; i += 256) {
        int idx = lo + i;
        if (idx < N_NODES && lh[i]) atomicAdd(&g[idx], lh[i]);
    }
}

__global__ void inv_sqrt_kernel(const int* __restrict__ deg, float* __restrict__ inv, int n) {
    int i = blockIdx.x * blockDim.x + threadIdx.x;
    if (i < n) inv[i] = rsqrtf(fmaxf((float)deg[i], 1.0f));
}

// ---------- phase A1: per-(block,bucket) counts ----------
__global__ __launch_bounds__(256) void countA_kernel(const int* __restrict__ dst,
        const int* __restrict__ ndst, int* __restrict__ counts) {
    __shared__ int lh[NBK];
    int blk = blockIdx.x;
    for (int i = threadIdx.x; i < NBK; i += 256) lh[i] = 0;
    __syncthreads();
    const int* dp = (blk < FB / 2) ? dst + blk * CH : ndst + (blk - FB / 2) * CH;
    const int4* dp4 = (const int4*)dp;
    for (int i = threadIdx.x; i < CH / 4; i += 256) {
        int4 v = dp4[i];
        atomicAdd(&lh[v.x >> BK_SH], 1);
        atomicAdd(&lh[v.y >> BK_SH], 1);
        atomicAdd(&lh[v.z >> BK_SH], 1);
        atomicAdd(&lh[v.w >> BK_SH], 1);
    }
    __syncthreads();
    for (int b = threadIdx.x; b < NBK; b += 256) counts[b * FB + blk] = lh[b];
}

// ---------- 3-stage scan over counts (bucket-major, L2S elements) ----------
__global__ __launch_bounds__(1024) void scanA2_kernel(const int* __restrict__ counts,
        int* __restrict__ offs, int* __restrict__ blockSums) {
    __shared__ int sh[1024];
    int t = threadIdx.x, b = blockIdx.x;
    int i = b * 1024 + t;                       // always < L2S (exact)
    int v = counts[i];
    sh[t] = v;
    __syncthreads();
    for (int off = 1; off < 1024; off <<= 1) {
        int u = (t >= off) ? sh[t - off] : 0;
        __syncthreads();
        sh[t] += u;
        __syncthreads();
    }
    offs[i] = sh[t] - v;
    if (t == 1023) blockSums[b] = sh[1023];
}

__global__ __launch_bounds__(512) void scanB2_kernel(const int* __restrict__ blockSums,
        int* __restrict__ blockOff) {
    __shared__ int sh[512];
    int t = threadIdx.x;
    int v = (t < SCB2) ? blockSums[t] : 0;
    sh[t] = v;
    __syncthreads();
    for (int off = 1; off < 512; off <<= 1) {
        int u = (t >= off) ? sh[t - off] : 0;
        __syncthreads();
        sh[t] += u;
        __syncthreads();
    }
    if (t < SCB2) blockOff[t] = sh[t] - v;
}

__global__ __launch_bounds__(1024) void scanC2_kernel(int* __restrict__ offs,
        const int* __restrict__ blockOff) {
    int b = blockIdx.x, t = threadIdx.x;
    int i = b * 1024 + t;
    offs[i] += blockOff[b];
    if (i == 0) offs[L2S] = 2 * E_EDGES;        // sentinel
}

// ---------- phase A2: place recs; each (bucket,block) run is block-private ----------
__global__ __launch_bounds__(256) void fillA2_kernel(const int* __restrict__ src, const int* __restrict__ dst,
        const int* __restrict__ nsrc, const int* __restrict__ ndst,
        const float* __restrict__ invs, const int* __restrict__ offs, int2* __restrict__ rec) {
    __shared__ int cur[NBK];
    __shared__ int base[NBK];
    int blk = blockIdx.x;
    int g = (blk >= FB / 2);
    const int* sp = g ? (nsrc + (blk - FB / 2) * CH) : (src + blk * CH);
    const int* dp = g ? (ndst + (blk - FB / 2) * CH) : (dst + blk * CH);
    const float* io = invs + (g ? 2 * N_NODES : 0);
    const float* ii = invs + (g ? 3 * N_NODES : N_NODES);
    const float sign = g ? -1.f : 1.f;
    for (int i = threadIdx.x; i < NBK; i += 256) {
        cur[i] = 0;
        base[i] = offs[i * FB + blk];
    }
    __syncthreads();
    for (int i = threadIdx.x; i < CH; i += 256) {
        int u = sp[i], v = dp[i];
        int b = v >> BK_SH;
        float c = sign * io[u] * ii[v];
        int p = base[b] + atomicAdd(&cur[b], 1);
        rec[p] = make_int2(u | ((v & (BK_N - 1)) << 17), __float_as_int(c));
    }
}

// ---------- MLP stage 1 ----------
__global__ __launch_bounds__(256) void mlp1_kernel(const float* __restrict__ in_feat,
        const float* __restrict__ W1, const float* __restrict__ b1,
        float* __restrict__ x, float* __restrict__ partials) {
    __shared__ float4 sRow4[MB_ROWS * 32];
    __shared__ float  sW1t[32 * 132];
    int tid = threadIdx.x;
    for (int idx = tid; idx < IN_F * HID; idx += 256) {
        int j = idx >> 5, k = idx & 31;
        sW1t[k * 132 + j] = W1[idx];
    }
    int nb = blockIdx.x * MB_ROWS;
    const float4* inf4 = (const float4*)in_feat;
    for (int idx = tid; idx < MB_ROWS * 32; idx += 256) {
        int row = idx >> 5, q = idx & 31;
        int g = nb + row;
        float4 v = (g < N_NODES) ? inf4[(size_t)g * 32 + q] : make_float4(0.f, 0.f, 0.f, 0.f);
        sRow4[row * 32 + (q ^ (row & 31))] = v;
    }
    __syncthreads();
    int rt = tid & 31, kt = tid >> 5;
    int k0 = kt * 4;
    float acc[2][4] = {{0.f}};
    const float4* w0p = (const float4*)&sW1t[(k0 + 0) * 132];
    const float4* w1p = (const float4*)&sW1t[(k0 + 1) * 132];
    const float4* w2p = (const float4*)&sW1t[(k0 + 2) * 132];
    const float4* w3p = (const float4*)&sW1t[(k0 + 3) * 132];
    #pragma unroll 4
    for (int jq = 0; jq < 32; ++jq) {
        int pq = jq ^ rt;
        float4 a0 = sRow4[rt * 32 + pq];
        float4 a1 = sRow4[(rt + 32) * 32 + pq];
        float4 w0 = w0p[jq], w1 = w1p[jq], w2 = w2p[jq], w3 = w3p[jq];
        acc[0][0] += a0.x*w0.x + a0.y*w0.y + a0.z*w0.z + a0.w*w0.w;
        acc[0][1] += a0.x*w1.x + a0.y*w1.y + a0.z*w1.z + a0.w*w1.w;
        acc[0][2] += a0.x*w2.x + a0.y*w2.y + a0.z*w2.z + a0.w*w2.w;
        acc[0][3] += a0.x*w3.x + a0.y*w3.y + a0.z*w3.z + a0.w*w3.w;
        acc[1][0] += a1.x*w0.x + a1.y*w0.y + a1.z*w0.z + a1.w*w0.w;
        acc[1][1] += a1.x*w1.x + a1.y*w1.y + a1.z*w1.z + a1.w*w1.w;
        acc[1][2] += a1.x*w2.x + a1.y*w2.y + a1.z*w2.z + a1.w*w2.w;
        acc[1][3] += a1.x*w3.x + a1.y*w3.y + a1.z*w3.z + a1.w*w3.w;
    }
    float bb[4] = { b1[k0], b1[k0 + 1], b1[k0 + 2], b1[k0 + 3] };
    float s[4] = {0.f, 0.f, 0.f, 0.f}, ss[4] = {0.f, 0.f, 0.f, 0.f};
    #pragma unroll
    for (int i = 0; i < 2; ++i) {
        int row = nb + rt + 32 * i;
        if (row < N_NODES) {
            float4 o;
            o.x = acc[i][0] + bb[0];
            o.y = acc[i][1] + bb[1];
            o.z = acc[i][2] + bb[2];
            o.w = acc[i][3] + bb[3];
            *(float4*)&x[(size_t)row * HID + k0] = o;
            s[0] += o.x; ss[0] += o.x * o.x;
            s[1] += o.y; ss[1] += o.y * o.y;
            s[2] += o.z; ss[2] += o.z * o.z;
            s[3] += o.w; ss[3] += o.w * o.w;
        }
    }
    for (int off = 16; off; off >>= 1) {
        #pragma unroll
        for (int c = 0; c < 4; ++c) {
            s[c]  += __shfl_down(s[c],  off, 32);
            ss[c] += __shfl_down(ss[c], off, 32);
        }
    }
    if (rt == 0) {
        float* pb = partials + (size_t)blockIdx.x * 64;
        #pragma unroll
        for (int c = 0; c < 4; ++c) {
            pb[k0 + c]      = s[c];
            pb[32 + k0 + c] = ss[c];
        }
    }
}

// ---------- reduce partials -> BN scale/shift ----------
__global__ __launch_bounds__(256) void bnparam_kernel(const float* __restrict__ partials,
        const float* __restrict__ gamma, const float* __restrict__ beta, float* __restrict__ params) {
    __shared__ float red[4][64];
    int t = threadIdx.x;
    int col = t & 63, ch = t >> 6;
    float sum = 0.f;
    for (int g = ch; g < MB_BLOCKS; g += 4) sum += partials[(size_t)g * 64 + col];
    red[ch][col] = sum;
    __syncthreads();
    if (t < 64) red[0][t] = red[0][t] + red[1][t] + red[2][t] + red[3][t];
    __syncthreads();
    if (t < HID) {
        float mu  = red[0][t] * (1.0f / (float)N_NODES);
        float var = red[0][t + 32] * (1.0f / (float)N_NODES) - mu * mu;
        float sg = gamma[t] * rsqrtf(var + 1e-5f);
        params[t]       = sg;
        params[HID + t] = beta[t] - mu * sg;
    }
}

// ---------- MLP stage 2: ori_h (fp32) + initial h (fp16) ----------
__global__ __launch_bounds__(256) void mlp2_kernel(const float* __restrict__ x,
        const float* __restrict__ params, const float* __restrict__ W2,
        const float* __restrict__ b2, float* __restrict__ ori_h, __half* __restrict__ h16) {
    __shared__ float sW2[HID * HID];
    __shared__ float sXn[8][HID];
    int tid = threadIdx.x;
    for (int i = tid; i < HID * HID; i += 256) sW2[i] = W2[i];
    int nb = blockIdx.x * 8;
    int k = tid & 31, r = tid >> 5;
    float v = x[(size_t)(nb + r) * HID + k];
    v = fmaxf(fmaf(v, params[k], params[HID + k]), 0.f);
    sXn[r][k] = v;
    __syncthreads();
    float acc = b2[k];
    #pragma unroll
    for (int j = 0; j < HID; ++j) acc = fmaf(sXn[r][j], sW2[j * HID + k], acc);
    int o = (nb + r) * HID + k;
    ori_h[o] = acc;
    h16[o] = __float2half(acc);
}

// ---------- propagation: block per bucket, LDS accumulators ----------
#define GT 512
__global__ __launch_bounds__(GT) void gatherB_kernel(const int* __restrict__ offs,
        const int2* __restrict__ rec, const __half* __restrict__ h,
        const float* __restrict__ ori, __half* __restrict__ hn16, float* __restrict__ out32) {
    __shared__ float acc[BK_N * HID];           // 16 KB
    int bkt = blockIdx.x;
    int tid = threadIdx.x;
    for (int i = tid; i < BK_N * HID; i += GT) acc[i] = 0.f;
    __syncthreads();
    int beg = offs[bkt * FB], end = offs[(bkt + 1) * FB];
    int hw = tid >> 5, f = tid & 31;            // 16 half-waves
    int n = end - beg;
    int pro = (n > 0 && (beg & 1)) ? 1 : 0;
    if (pro && hw == 0) {
        int2 r = rec[beg];
        int u = r.x & 0x1FFFF, dl = r.x >> 17;
        atomicAdd(&acc[dl * HID + f], __int_as_float(r.y) * __half2float(h[u * HID + f]));
    }
    int s = beg + pro;
    int m = end - s;
    int ng = m >> 2;
    for (int gi = hw; gi < ng; gi += 16) {
        int i = s + gi * 4;
        int4 a = *(const int4*)(rec + i);
        int4 b = *(const int4*)(rec + i + 2);
        int u0 = a.x & 0x1FFFF, d0 = a.x >> 17;
        int u1 = a.z & 0x1FFFF, d1 = a.z >> 17;
        int u2 = b.x & 0x1FFFF, d2 = b.x >> 17;
        int u3 = b.z & 0x1FFFF, d3 = b.z >> 17;
        float h0 = __half2float(h[u0 * HID + f]);
        float h1 = __half2float(h[u1 * HID + f]);
        float h2 = __half2float(h[u2 * HID + f]);
        float h3 = __half2float(h[u3 * HID + f]);
        atomicAdd(&acc[d0 * HID + f], __int_as_float(a.y) * h0);
        atomicAdd(&acc[d1 * HID + f], __int_as_float(a.w) * h1);
        atomicAdd(&acc[d2 * HID + f], __int_as_float(b.y) * h2);
        atomicAdd(&acc[d3 * HID + f], __int_as_float(b.w) * h3);
    }
    int rem = m & 3;
    if (hw < rem) {
        int i = s + ng * 4 + hw;
        int2 r = rec[i];
        int u = r.x & 0x1FFFF, dl = r.x >> 17;
        atomicAdd(&acc[dl * HID + f], __int_as_float(r.y) * __half2float(h[u * HID + f]));
    }
    __syncthreads();
    int lo = bkt * BK_N;
    int cnt = min(BK_N, N_NODES - lo);
    for (int i = tid; i < cnt * HID; i += GT) {
        float v = ori[lo * HID + i] + acc[i];
        if (out32) out32[lo * HID + i] = v;
        else hn16[lo * HID + i] = __float2half(v);
    }
}

extern "C" void kernel_launch(void* const* d_in, const int* in_sizes, int n_in,
                              void* d_out, int out_size, void* d_ws, size_t ws_size,
                              hipStream_t stream) {
    const float* in_feat = (const float*)d_in[0];
    const float* W1    = (const float*)d_in[1];
    const float* b1    = (const float*)d_in[2];
    const float* gamma = (const float*)d_in[3];
    const float* beta  = (const float*)d_in[4];
    const float* W2    = (const float*)d_in[5];
    const float* b2    = (const float*)d_in[6];
    const int* src  = (const int*)d_in[7];
    const int* dst  = (const int*)d_in[8];
    const int* nsrc = (const int*)d_in[9];
    const int* ndst = (const int*)d_in[10];
    float* out = (float*)d_out;

    // ---- workspace layout ----
    float* ws      = (float*)d_ws;
    float* x       = ws;                                   // N*32 (also overlays counts before mlp1)
    float* ori_h   = x + (size_t)N_NODES * HID;            // N*32
    float* invs    = ori_h + (size_t)N_NODES * HID;        // 4*N
    float* params  = invs + 4 * (size_t)N_NODES;           // 64
    float* partials= params + 2 * HID;                     // MB_BLOCKS*64
    int*   degs    = (int*)(partials + (size_t)MB_BLOCKS * 64);  // 4*N
    int*   offs    = degs + 4 * N_NODES;                   // L2S+1
    int*   blockSums = offs + L2S + 2;                     // 512
    int*   blockOff  = blockSums + 512;                    // 512
    __half* h16A   = (__half*)(blockOff + 512);            // N*32 fp16
    __half* h16B   = h16A + (size_t)N_NODES * HID;
    uintptr_t rp  = (uintptr_t)(h16B + (size_t)N_NODES * HID);
    rp = (rp + 15) & ~(uintptr_t)15;
    int2*  rec    = (int2*)rp;                             // 2*E records (51.2 MB)
    int*   counts = (int*)x;                               // L2S ints; dead before mlp1 writes x

    hipMemsetAsync(degs, 0, 4 * (size_t)N_NODES * sizeof(int), stream);

    hist_kernel<<<NWIN * 4 * HS, 256, 0, stream>>>(src, dst, nsrc, ndst, degs);
    inv_sqrt_kernel<<<(4 * N_NODES + 255) / 256, 256, 0, stream>>>(degs, invs, 4 * N_NODES);

    countA_kernel<<<FB, 256, 0, stream>>>(dst, ndst, counts);
    scanA2_kernel<<<SCB2, 1024, 0, stream>>>(counts, offs, blockSums);
    scanB2_kernel<<<1, 512, 0, stream>>>(blockSums, blockOff);
    scanC2_kernel<<<SCB2, 1024, 0, stream>>>(offs, blockOff);
    fillA2_kernel<<<FB, 256, 0, stream>>>(src, dst, nsrc, ndst, invs, offs, rec);

    mlp1_kernel<<<MB_BLOCKS, 256, 0, stream>>>(in_feat, W1, b1, x, partials);
    bnparam_kernel<<<1, 256, 0, stream>>>(partials, gamma, beta, params);
    mlp2_kernel<<<N_NODES / 8, 256, 0, stream>>>(x, params, W2, b2, ori_h, h16A);

    const __half* h = h16A;
    for (int it = 0; it < PROP; ++it) {
        __half* hn16 = (it & 1) ? h16A : h16B;
        float* o32 = (it == PROP - 1) ? out : nullptr;
        gatherB_kernel<<<NBK, GT, 0, stream>>>(offs, rec, h, ori_h, hn16, o32);
        h = hn16;
    }
}

// Round 8
// 1333.625 us; speedup vs baseline: 8.4179x; 8.4179x over previous
//
#include <hip/hip_runtime.h>
#include <hip/hip_fp16.h>

#define N_NODES 100000
#define E_EDGES 3200000
#define IN_F 128
#define HID 32
#define PROP 8

#define WIN 16384          // hist window (64 KB LDS)
#define NWIN 7
#define HS 16

#define MB_ROWS 64
#define MB_BLOCKS ((N_NODES + MB_ROWS - 1) / MB_ROWS)   // 1563

// ---- binning geometry ----
#define FB 512             // fill blocks; CH edges each
#define CH 12500           // 2E / FB
#define BK_SH 7
#define BK_N 128           // nodes per bucket
#define NBK 782            // ceil(N / 128)
#define L2S (NBK * FB)     // 400384 = 391*1024 exactly
#define SCB2 391

// ---------- windowed degree histogram ----------
__global__ __launch_bounds__(256) void hist_kernel(const int* __restrict__ s, const int* __restrict__ d,
        const int* __restrict__ ns, const int* __restrict__ nd, int* __restrict__ degs) {
    __shared__ int lh[WIN];
    int b = blockIdx.x;
    int w = b % NWIN;
    int st = (b / NWIN) % 4;
    int sl = b / (NWIN * 4);
    const int* p = (st == 0) ? s : (st == 1) ? d : (st == 2) ? ns : nd;
    for (int i = threadIdx.x; i < WIN; i += 256) lh[i] = 0;
    __syncthreads();
    const int lo = w * WIN;
    const int per = E_EDGES / HS;
    const int4* p4 = (const int4*)(p + sl * per);
    for (int i = threadIdx.x; i < per / 4; i += 256) {
        int4 v = p4[i];
        int a;
        a = v.x - lo; if ((unsigned)a < WIN) atomicAdd(&lh[a], 1);
        a = v.y - lo; if ((unsigned)a < WIN) atomicAdd(&lh[a], 1);
        a = v.z - lo; if ((unsigned)a < WIN) atomicAdd(&lh[a], 1);
        a = v.w - lo; if ((unsigned)a < WIN) atomicAdd(&lh[a], 1);
    }
    __syncthreads();
    int* g = degs + st * N_NODES;
    for (int i = threadIdx.x; i < WIN; i += 256) {
        int idx = lo + i;
        if (idx < N_NODES && lh[i]) atomicAdd(&g[idx], lh[i]);
    }
}

__global__ void inv_sqrt_kernel(const int* __restrict__ deg, float* __restrict__ inv, int n) {
    int i = blockIdx.x * blockDim.x + threadIdx.x;
    if (i < n) inv[i] = rsqrtf(fmaxf((float)deg[i], 1.0f));
}

// ---------- phase A1: per-(block,bucket) counts ----------
__global__ __launch_bounds__(256) void countA_kernel(const int* __restrict__ dst,
        const int* __restrict__ ndst, int* __restrict__ counts) {
    __shared__ int lh[NBK];
    int blk = blockIdx.x;
    for (int i = threadIdx.x; i < NBK; i += 256) lh[i] = 0;
    __syncthreads();
    const int* dp = (blk < FB / 2) ? dst + blk * CH : ndst + (blk - FB / 2) * CH;
    const int4* dp4 = (const int4*)dp;
    for (int i = threadIdx.x; i < CH / 4; i += 256) {
        int4 v = dp4[i];
        atomicAdd(&lh[v.x >> BK_SH], 1);
        atomicAdd(&lh[v.y >> BK_SH], 1);
        atomicAdd(&lh[v.z >> BK_SH], 1);
        atomicAdd(&lh[v.w >> BK_SH], 1);
    }
    __syncthreads();
    for (int b = threadIdx.x; b < NBK; b += 256) counts[b * FB + blk] = lh[b];
}

// ---------- 3-stage scan over counts (bucket-major, L2S elements) ----------
__global__ __launch_bounds__(1024) void scanA2_kernel(const int* __restrict__ counts,
        int* __restrict__ offs, int* __restrict__ blockSums) {
    __shared__ int sh[1024];
    int t = threadIdx.x, b = blockIdx.x;
    int i = b * 1024 + t;
    int v = counts[i];
    sh[t] = v;
    __syncthreads();
    for (int off = 1; off < 1024; off <<= 1) {
        int u = (t >= off) ? sh[t - off] : 0;
        __syncthreads();
        sh[t] += u;
        __syncthreads();
    }
    offs[i] = sh[t] - v;
    if (t == 1023) blockSums[b] = sh[1023];
}

__global__ __launch_bounds__(512) void scanB2_kernel(const int* __restrict__ blockSums,
        int* __restrict__ blockOff) {
    __shared__ int sh[512];
    int t = threadIdx.x;
    int v = (t < SCB2) ? blockSums[t] : 0;
    sh[t] = v;
    __syncthreads();
    for (int off = 1; off < 512; off <<= 1) {
        int u = (t >= off) ? sh[t - off] : 0;
        __syncthreads();
        sh[t] += u;
        __syncthreads();
    }
    if (t < SCB2) blockOff[t] = sh[t] - v;
}

__global__ __launch_bounds__(1024) void scanC2_kernel(int* __restrict__ offs,
        const int* __restrict__ blockOff) {
    int b = blockIdx.x, t = threadIdx.x;
    int i = b * 1024 + t;
    offs[i] += blockOff[b];
    if (i == 0) offs[L2S] = 2 * E_EDGES;        // sentinel
}

// ---------- phase A2: place recs; each (bucket,block) run is block-private ----------
__global__ __launch_bounds__(256) void fillA2_kernel(const int* __restrict__ src, const int* __restrict__ dst,
        const int* __restrict__ nsrc, const int* __restrict__ ndst,
        const float* __restrict__ invs, const int* __restrict__ offs, int2* __restrict__ rec) {
    __shared__ int cur[NBK];
    __shared__ int base[NBK];
    int blk = blockIdx.x;
    int g = (blk >= FB / 2);
    const int* sp = g ? (nsrc + (blk - FB / 2) * CH) : (src + blk * CH);
    const int* dp = g ? (ndst + (blk - FB / 2) * CH) : (dst + blk * CH);
    const float* io = invs + (g ? 2 * N_NODES : 0);
    const float* ii = invs + (g ? 3 * N_NODES : N_NODES);
    const float sign = g ? -1.f : 1.f;
    for (int i = threadIdx.x; i < NBK; i += 256) {
        cur[i] = 0;
        base[i] = offs[i * FB + blk];
    }
    __syncthreads();
    for (int i = threadIdx.x; i < CH; i += 256) {
        int u = sp[i], v = dp[i];
        int b = v >> BK_SH;
        float c = sign * io[u] * ii[v];
        int p = base[b] + atomicAdd(&cur[b], 1);        // int LDS atomic: native
        rec[p] = make_int2(u | ((v & (BK_N - 1)) << 17), __float_as_int(c));
    }
}

// ---------- in-bucket reorder: bucket-major rec -> node-major rec2 + row_ptr2 ----------
__global__ __launch_bounds__(256) void reorder_kernel(const int* __restrict__ offs,
        const int2* __restrict__ rec, int2* __restrict__ rec2, int* __restrict__ row_ptr2) {
    __shared__ int cnt[BK_N];
    __shared__ int scan[BK_N];
    __shared__ int base[BK_N];
    int bkt = blockIdx.x, tid = threadIdx.x;
    if (tid < BK_N) cnt[tid] = 0;
    __syncthreads();
    int beg = offs[bkt * FB], end = offs[(bkt + 1) * FB];
    for (int i = beg + tid; i < end; i += 256)
        atomicAdd(&cnt[rec[i].x >> 17], 1);             // int LDS atomic: native
    __syncthreads();
    int v = (tid < BK_N) ? cnt[tid] : 0;
    if (tid < BK_N) scan[tid] = v;
    __syncthreads();
    for (int off = 1; off < BK_N; off <<= 1) {
        int u = (tid < BK_N && tid >= off) ? scan[tid - off] : 0;
        __syncthreads();
        if (tid < BK_N) scan[tid] += u;
        __syncthreads();
    }
    if (tid < BK_N) {
        int b = beg + scan[tid] - v;                    // exclusive
        base[tid] = b;
        row_ptr2[bkt * BK_N + tid] = b;
        cnt[tid] = 0;                                   // reuse as cursor
    }
    if (bkt == NBK - 1 && tid == 0) row_ptr2[NBK * BK_N] = 2 * E_EDGES;
    __syncthreads();
    for (int i = beg + tid; i < end; i += 256) {
        int2 r = rec[i];
        int d = r.x >> 17;
        int p = base[d] + atomicAdd(&cnt[d], 1);        // ds_add_rtn_u32
        rec2[p] = make_int2(r.x & 0x1FFFF, r.y);
    }
}

// ---------- MLP stage 1 ----------
__global__ __launch_bounds__(256) void mlp1_kernel(const float* __restrict__ in_feat,
        const float* __restrict__ W1, const float* __restrict__ b1,
        float* __restrict__ x, float* __restrict__ partials) {
    __shared__ float4 sRow4[MB_ROWS * 32];
    __shared__ float  sW1t[32 * 132];
    int tid = threadIdx.x;
    for (int idx = tid; idx < IN_F * HID; idx += 256) {
        int j = idx >> 5, k = idx & 31;
        sW1t[k * 132 + j] = W1[idx];
    }
    int nb = blockIdx.x * MB_ROWS;
    const float4* inf4 = (const float4*)in_feat;
    for (int idx = tid; idx < MB_ROWS * 32; idx += 256) {
        int row = idx >> 5, q = idx & 31;
        int g = nb + row;
        float4 v = (g < N_NODES) ? inf4[(size_t)g * 32 + q] : make_float4(0.f, 0.f, 0.f, 0.f);
        sRow4[row * 32 + (q ^ (row & 31))] = v;
    }
    __syncthreads();
    int rt = tid & 31, kt = tid >> 5;
    int k0 = kt * 4;
    float acc[2][4] = {{0.f}};
    const float4* w0p = (const float4*)&sW1t[(k0 + 0) * 132];
    const float4* w1p = (const float4*)&sW1t[(k0 + 1) * 132];
    const float4* w2p = (const float4*)&sW1t[(k0 + 2) * 132];
    const float4* w3p = (const float4*)&sW1t[(k0 + 3) * 132];
    #pragma unroll 4
    for (int jq = 0; jq < 32; ++jq) {
        int pq = jq ^ rt;
        float4 a0 = sRow4[rt * 32 + pq];
        float4 a1 = sRow4[(rt + 32) * 32 + pq];
        float4 w0 = w0p[jq], w1 = w1p[jq], w2 = w2p[jq], w3 = w3p[jq];
        acc[0][0] += a0.x*w0.x + a0.y*w0.y + a0.z*w0.z + a0.w*w0.w;
        acc[0][1] += a0.x*w1.x + a0.y*w1.y + a0.z*w1.z + a0.w*w1.w;
        acc[0][2] += a0.x*w2.x + a0.y*w2.y + a0.z*w2.z + a0.w*w2.w;
        acc[0][3] += a0.x*w3.x + a0.y*w3.y + a0.z*w3.z + a0.w*w3.w;
        acc[1][0] += a1.x*w0.x + a1.y*w0.y + a1.z*w0.z + a1.w*w0.w;
        acc[1][1] += a1.x*w1.x + a1.y*w1.y + a1.z*w1.z + a1.w*w1.w;
        acc[1][2] += a1.x*w2.x + a1.y*w2.y + a1.z*w2.z + a1.w*w2.w;
        acc[1][3] += a1.x*w3.x + a1.y*w3.y + a1.z*w3.z + a1.w*w3.w;
    }
    float bb[4] = { b1[k0], b1[k0 + 1], b1[k0 + 2], b1[k0 + 3] };
    float s[4] = {0.f, 0.f, 0.f, 0.f}, ss[4] = {0.f, 0.f, 0.f, 0.f};
    #pragma unroll
    for (int i = 0; i < 2; ++i) {
        int row = nb + rt + 32 * i;
        if (row < N_NODES) {
            float4 o;
            o.x = acc[i][0] + bb[0];
            o.y = acc[i][1] + bb[1];
            o.z = acc[i][2] + bb[2];
            o.w = acc[i][3] + bb[3];
            *(float4*)&x[(size_t)row * HID + k0] = o;
            s[0] += o.x; ss[0] += o.x * o.x;
            s[1] += o.y; ss[1] += o.y * o.y;
            s[2] += o.z; ss[2] += o.z * o.z;
            s[3] += o.w; ss[3] += o.w * o.w;
        }
    }
    for (int off = 16; off; off >>= 1) {
        #pragma unroll
        for (int c = 0; c < 4; ++c) {
            s[c]  += __shfl_down(s[c],  off, 32);
            ss[c] += __shfl_down(ss[c], off, 32);
        }
    }
    if (rt == 0) {
        float* pb = partials + (size_t)blockIdx.x * 64;
        #pragma unroll
        for (int c = 0; c < 4; ++c) {
            pb[k0 + c]      = s[c];
            pb[32 + k0 + c] = ss[c];
        }
    }
}

// ---------- reduce partials -> BN scale/shift ----------
__global__ __launch_bounds__(256) void bnparam_kernel(const float* __restrict__ partials,
        const float* __restrict__ gamma, const float* __restrict__ beta, float* __restrict__ params) {
    __shared__ float red[4][64];
    int t = threadIdx.x;
    int col = t & 63, ch = t >> 6;
    float sum = 0.f;
    for (int g = ch; g < MB_BLOCKS; g += 4) sum += partials[(size_t)g * 64 + col];
    red[ch][col] = sum;
    __syncthreads();
    if (t < 64) red[0][t] = red[0][t] + red[1][t] + red[2][t] + red[3][t];
    __syncthreads();
    if (t < HID) {
        float mu  = red[0][t] * (1.0f / (float)N_NODES);
        float var = red[0][t + 32] * (1.0f / (float)N_NODES) - mu * mu;
        float sg = gamma[t] * rsqrtf(var + 1e-5f);
        params[t]       = sg;
        params[HID + t] = beta[t] - mu * sg;
    }
}

// ---------- MLP stage 2: ori_h (fp32) + initial h (fp16) ----------
__global__ __launch_bounds__(256) void mlp2_kernel(const float* __restrict__ x,
        const float* __restrict__ params, const float* __restrict__ W2,
        const float* __restrict__ b2, float* __restrict__ ori_h, __half* __restrict__ h16) {
    __shared__ float sW2[HID * HID];
    __shared__ float sXn[8][HID];
    int tid = threadIdx.x;
    for (int i = tid; i < HID * HID; i += 256) sW2[i] = W2[i];
    int nb = blockIdx.x * 8;
    int k = tid & 31, r = tid >> 5;
    float v = x[(size_t)(nb + r) * HID + k];
    v = fmaxf(fmaf(v, params[k], params[HID + k]), 0.f);
    sXn[r][k] = v;
    __syncthreads();
    float acc = b2[k];
    #pragma unroll
    for (int j = 0; j < HID; ++j) acc = fmaf(sXn[r][j], sW2[j * HID + k], acc);
    int o = (nb + r) * HID + k;
    ori_h[o] = acc;
    h16[o] = __float2half(acc);
}

// ---------- propagation: half-wave per node, 8-way ILP, fp16 h, no atomics ----------
__global__ __launch_bounds__(256) void gather_kernel(const int* __restrict__ row_ptr,
        const int2* __restrict__ rec, const __half* __restrict__ h,
        const float* __restrict__ ori, __half* __restrict__ hn16, float* __restrict__ out32) {
    int tid = threadIdx.x;
    int node = blockIdx.x * 8 + (tid >> 5);
    int f = tid & 31;
    int beg = row_ptr[node], end = row_ptr[node + 1];
    float acc0 = 0.f, acc1 = 0.f, acc2 = 0.f, acc3 = 0.f;
    float acc4 = 0.f, acc5 = 0.f, acc6 = 0.f, acc7 = 0.f;
    int i = beg;
    if ((i & 1) && i < end) {                    // align rec reads to 16 B
        int2 r = rec[i];
        acc0 = fmaf(__int_as_float(r.y), __half2float(h[r.x * HID + f]), acc0);
        ++i;
    }
    for (; i + 8 <= end; i += 8) {
        int4 a = *(const int4*)(rec + i);
        int4 b = *(const int4*)(rec + i + 2);
        int4 c = *(const int4*)(rec + i + 4);
        int4 d = *(const int4*)(rec + i + 6);
        float h0 = __half2float(h[a.x * HID + f]);
        float h1 = __half2float(h[a.z * HID + f]);
        float h2 = __half2float(h[b.x * HID + f]);
        float h3 = __half2float(h[b.z * HID + f]);
        float h4 = __half2float(h[c.x * HID + f]);
        float h5 = __half2float(h[c.z * HID + f]);
        float h6 = __half2float(h[d.x * HID + f]);
        float h7 = __half2float(h[d.z * HID + f]);
        acc0 = fmaf(__int_as_float(a.y), h0, acc0);
        acc1 = fmaf(__int_as_float(a.w), h1, acc1);
        acc2 = fmaf(__int_as_float(b.y), h2, acc2);
        acc3 = fmaf(__int_as_float(b.w), h3, acc3);
        acc4 = fmaf(__int_as_float(c.y), h4, acc4);
        acc5 = fmaf(__int_as_float(c.w), h5, acc5);
        acc6 = fmaf(__int_as_float(d.y), h6, acc6);
        acc7 = fmaf(__int_as_float(d.w), h7, acc7);
    }
    for (; i + 4 <= end; i += 4) {
        int4 a = *(const int4*)(rec + i);
        int4 b = *(const int4*)(rec + i + 2);
        acc0 = fmaf(__int_as_float(a.y), __half2float(h[a.x * HID + f]), acc0);
        acc1 = fmaf(__int_as_float(a.w), __half2float(h[a.z * HID + f]), acc1);
        acc2 = fmaf(__int_as_float(b.y), __half2float(h[b.x * HID + f]), acc2);
        acc3 = fmaf(__int_as_float(b.w), __half2float(h[b.z * HID + f]), acc3);
    }
    for (; i < end; ++i) {
        int2 r = rec[i];
        acc0 = fmaf(__int_as_float(r.y), __half2float(h[r.x * HID + f]), acc0);
    }
    int o = node * HID + f;
    float r0 = (acc0 + acc1) + (acc2 + acc3);
    float r1 = (acc4 + acc5) + (acc6 + acc7);
    float res = ori[o] + (r0 + r1);
    if (out32) out32[o] = res;
    else hn16[o] = __float2half(res);
}

extern "C" void kernel_launch(void* const* d_in, const int* in_sizes, int n_in,
                              void* d_out, int out_size, void* d_ws, size_t ws_size,
                              hipStream_t stream) {
    const float* in_feat = (const float*)d_in[0];
    const float* W1    = (const float*)d_in[1];
    const float* b1    = (const float*)d_in[2];
    const float* gamma = (const float*)d_in[3];
    const float* beta  = (const float*)d_in[4];
    const float* W2    = (const float*)d_in[5];
    const float* b2    = (const float*)d_in[6];
    const int* src  = (const int*)d_in[7];
    const int* dst  = (const int*)d_in[8];
    const int* nsrc = (const int*)d_in[9];
    const int* ndst = (const int*)d_in[10];
    float* out = (float*)d_out;

    // ---- workspace layout ----
    float* ws      = (float*)d_ws;
    float* x       = ws;                                   // N*32 (counts overlay pre-mlp1)
    float* ori_h   = x + (size_t)N_NODES * HID;            // N*32
    float* invs    = ori_h + (size_t)N_NODES * HID;        // 4*N
    float* params  = invs + 4 * (size_t)N_NODES;           // 64
    float* partials= params + 2 * HID;                     // MB_BLOCKS*64
    int*   degs    = (int*)(partials + (size_t)MB_BLOCKS * 64);  // 4*N
    int*   offs    = degs + 4 * N_NODES;                   // L2S+1
    int*   blockSums = offs + L2S + 2;                     // 512
    int*   blockOff  = blockSums + 512;                    // 512
    int*   row_ptr2  = blockOff + 512;                     // NBK*128+1
    __half* h16A   = (__half*)(row_ptr2 + NBK * BK_N + 2); // N*32 fp16
    __half* h16B   = h16A + (size_t)N_NODES * HID;
    uintptr_t rp  = (uintptr_t)(h16B + (size_t)N_NODES * HID);
    rp = (rp + 15) & ~(uintptr_t)15;
    int2*  rec    = (int2*)rp;                             // 2*E records (51.2 MB, bucket-major)
    int*   counts = (int*)x;                               // L2S ints; dead before mlp1 writes x
    int2*  rec2   = (int2*)in_feat;                        // 51.2 MB, reused after mlp1 (harness
                                                           // restores inputs before every launch)

    hipMemsetAsync(degs, 0, 4 * (size_t)N_NODES * sizeof(int), stream);

    hist_kernel<<<NWIN * 4 * HS, 256, 0, stream>>>(src, dst, nsrc, ndst, degs);
    inv_sqrt_kernel<<<(4 * N_NODES + 255) / 256, 256, 0, stream>>>(degs, invs, 4 * N_NODES);

    countA_kernel<<<FB, 256, 0, stream>>>(dst, ndst, counts);
    scanA2_kernel<<<SCB2, 1024, 0, stream>>>(counts, offs, blockSums);
    scanB2_kernel<<<1, 512, 0, stream>>>(blockSums, blockOff);
    scanC2_kernel<<<SCB2, 1024, 0, stream>>>(offs, blockOff);
    fillA2_kernel<<<FB, 256, 0, stream>>>(src, dst, nsrc, ndst, invs, offs, rec);

    mlp1_kernel<<<MB_BLOCKS, 256, 0, stream>>>(in_feat, W1, b1, x, partials);
    bnparam_kernel<<<1, 256, 0, stream>>>(partials, gamma, beta, params);
    mlp2_kernel<<<N_NODES / 8, 256, 0, stream>>>(x, params, W2, b2, ori_h, h16A);

    // reorder after mlp1 (in_feat dead) -> node-major CSR in rec2 + row_ptr2
    reorder_kernel<<<NBK, 256, 0, stream>>>(offs, rec, rec2, row_ptr2);

    const __half* h = h16A;
    for (int it = 0; it < PROP; ++it) {
        __half* hn16 = (it & 1) ? h16A : h16B;
        float* o32 = (it == PROP - 1) ? out : nullptr;
        gather_kernel<<<N_NODES / 8, 256, 0, stream>>>(row_ptr2, rec2, h, ori_h, hn16, o32);
        h = hn16;
    }
}

// Round 9
// 1251.099 us; speedup vs baseline: 8.9732x; 1.0660x over previous
//
#include <hip/hip_runtime.h>
#include <hip/hip_fp16.h>

#define N_NODES 100000
#define E_EDGES 3200000
#define IN_F 128
#define HID 32
#define PROP 8

#define WIN 16384          // hist window (64 KB LDS)
#define NWIN 7
#define HS 32              // slices per stream (448 blocks total, 2 streams)

#define MB_ROWS 64
#define MB_BLOCKS ((N_NODES + MB_ROWS - 1) / MB_ROWS)   // 1563

// ---- binning geometry ----
#define FB 512             // fill blocks; CH edges each
#define CH 12500           // 2E / FB
#define BK_SH 7
#define BK_N 128           // nodes per bucket
#define NBK 782            // ceil(N / 128)
#define L2S (NBK * FB)     // 400384 = 391*1024 exactly
#define SCB2 391

// ---------- windowed out-degree histogram (src + nsrc only) ----------
__global__ __launch_bounds__(256) void hist_kernel(const int* __restrict__ s,
        const int* __restrict__ ns, int* __restrict__ degs) {
    __shared__ int lh[WIN];
    int b = blockIdx.x;
    int w = b % NWIN;
    int st = (b / NWIN) % 2;
    int sl = b / (NWIN * 2);
    const int* p = st ? ns : s;
    for (int i = threadIdx.x; i < WIN; i += 256) lh[i] = 0;
    __syncthreads();
    const int lo = w * WIN;
    const int per = E_EDGES / HS;               // 100000, /4 ok
    const int4* p4 = (const int4*)(p + sl * per);
    for (int i = threadIdx.x; i < per / 4; i += 256) {
        int4 v = p4[i];
        int a;
        a = v.x - lo; if ((unsigned)a < WIN) atomicAdd(&lh[a], 1);
        a = v.y - lo; if ((unsigned)a < WIN) atomicAdd(&lh[a], 1);
        a = v.z - lo; if ((unsigned)a < WIN) atomicAdd(&lh[a], 1);
        a = v.w - lo; if ((unsigned)a < WIN) atomicAdd(&lh[a], 1);
    }
    __syncthreads();
    int* g = degs + st * N_NODES;
    for (int i = threadIdx.x; i < WIN; i += 256) {
        int idx = lo + i;
        if (idx < N_NODES && lh[i]) atomicAdd(&g[idx], lh[i]);
    }
}

__global__ void inv_sqrt_kernel(const int* __restrict__ deg, float* __restrict__ inv, int n) {
    int i = blockIdx.x * blockDim.x + threadIdx.x;
    if (i < n) inv[i] = rsqrtf(fmaxf((float)deg[i], 1.0f));
}

// ---------- phase A1: per-(block,bucket) counts ----------
__global__ __launch_bounds__(256) void countA_kernel(const int* __restrict__ dst,
        const int* __restrict__ ndst, int* __restrict__ counts) {
    __shared__ int lh[NBK];
    int blk = blockIdx.x;
    for (int i = threadIdx.x; i < NBK; i += 256) lh[i] = 0;
    __syncthreads();
    const int* dp = (blk < FB / 2) ? dst + blk * CH : ndst + (blk - FB / 2) * CH;
    const int4* dp4 = (const int4*)dp;
    for (int i = threadIdx.x; i < CH / 4; i += 256) {
        int4 v = dp4[i];
        atomicAdd(&lh[v.x >> BK_SH], 1);
        atomicAdd(&lh[v.y >> BK_SH], 1);
        atomicAdd(&lh[v.z >> BK_SH], 1);
        atomicAdd(&lh[v.w >> BK_SH], 1);
    }
    __syncthreads();
    for (int b = threadIdx.x; b < NBK; b += 256) counts[b * FB + blk] = lh[b];
}

// ---------- 3-stage scan over counts (bucket-major, L2S elements) ----------
__global__ __launch_bounds__(1024) void scanA2_kernel(const int* __restrict__ counts,
        int* __restrict__ offs, int* __restrict__ blockSums) {
    __shared__ int sh[1024];
    int t = threadIdx.x, b = blockIdx.x;
    int i = b * 1024 + t;
    int v = counts[i];
    sh[t] = v;
    __syncthreads();
    for (int off = 1; off < 1024; off <<= 1) {
        int u = (t >= off) ? sh[t - off] : 0;
        __syncthreads();
        sh[t] += u;
        __syncthreads();
    }
    offs[i] = sh[t] - v;
    if (t == 1023) blockSums[b] = sh[1023];
}

__global__ __launch_bounds__(512) void scanB2_kernel(const int* __restrict__ blockSums,
        int* __restrict__ blockOff) {
    __shared__ int sh[512];
    int t = threadIdx.x;
    int v = (t < SCB2) ? blockSums[t] : 0;
    sh[t] = v;
    __syncthreads();
    for (int off = 1; off < 512; off <<= 1) {
        int u = (t >= off) ? sh[t - off] : 0;
        __syncthreads();
        sh[t] += u;
        __syncthreads();
    }
    if (t < SCB2) blockOff[t] = sh[t] - v;
}

__global__ __launch_bounds__(1024) void scanC2_kernel(int* __restrict__ offs,
        const int* __restrict__ blockOff) {
    int b = blockIdx.x, t = threadIdx.x;
    int i = b * 1024 + t;
    offs[i] += blockOff[b];
    if (i == 0) offs[L2S] = 2 * E_EDGES;        // sentinel
}

// ---------- phase A2: place recs (coef' = sign*inv_out[u]; graph bit 24) ----------
__global__ __launch_bounds__(256) void fillA2_kernel(const int* __restrict__ src, const int* __restrict__ dst,
        const int* __restrict__ nsrc, const int* __restrict__ ndst,
        const float* __restrict__ invs, const int* __restrict__ offs, int2* __restrict__ rec) {
    __shared__ int cur[NBK];
    __shared__ int base[NBK];
    int blk = blockIdx.x;
    int g = (blk >= FB / 2);
    const int* sp = g ? (nsrc + (blk - FB / 2) * CH) : (src + blk * CH);
    const int* dp = g ? (ndst + (blk - FB / 2) * CH) : (dst + blk * CH);
    const float* io = invs + (g ? N_NODES : 0);
    const float sign = g ? -1.f : 1.f;
    const int gbit = g << 24;
    for (int i = threadIdx.x; i < NBK; i += 256) {
        cur[i] = 0;
        base[i] = offs[i * FB + blk];
    }
    __syncthreads();
    for (int i = threadIdx.x; i < CH; i += 256) {
        int u = sp[i], v = dp[i];
        int b = v >> BK_SH;
        float c = sign * io[u];
        int p = base[b] + atomicAdd(&cur[b], 1);        // int LDS atomic: native
        rec[p] = make_int2(u | ((v & (BK_N - 1)) << 17) | gbit, __float_as_int(c));
    }
}

// ---------- in-bucket reorder: node-major rec2 + row_ptr2, fold inv_in ----------
__global__ __launch_bounds__(256) void reorder_kernel(const int* __restrict__ offs,
        const int2* __restrict__ rec, int2* __restrict__ rec2, int* __restrict__ row_ptr2) {
    __shared__ int cnt[BK_N];
    __shared__ int cntp[BK_N];
    __shared__ int scan[BK_N];
    __shared__ int base[BK_N];
    __shared__ float invp[BK_N], invn[BK_N];
    int bkt = blockIdx.x, tid = threadIdx.x;
    if (tid < BK_N) { cnt[tid] = 0; cntp[tid] = 0; }
    __syncthreads();
    int beg = offs[bkt * FB], end = offs[(bkt + 1) * FB];
    for (int i = beg + tid; i < end; i += 256) {
        int rx = rec[i].x;
        int d = (rx >> 17) & (BK_N - 1);
        atomicAdd(&cnt[d], 1);
        if (!(rx & (1 << 24))) atomicAdd(&cntp[d], 1);
    }
    __syncthreads();
    int v = (tid < BK_N) ? cnt[tid] : 0;
    if (tid < BK_N) {
        scan[tid] = v;
        int np = cntp[tid];
        invp[tid] = rsqrtf(fmaxf((float)np, 1.0f));
        invn[tid] = rsqrtf(fmaxf((float)(v - np), 1.0f));
    }
    __syncthreads();
    for (int off = 1; off < BK_N; off <<= 1) {
        int u = (tid < BK_N && tid >= off) ? scan[tid - off] : 0;
        __syncthreads();
        if (tid < BK_N) scan[tid] += u;
        __syncthreads();
    }
    if (tid < BK_N) {
        int b = beg + scan[tid] - v;                    // exclusive
        base[tid] = b;
        row_ptr2[bkt * BK_N + tid] = b;
        cnt[tid] = 0;                                   // reuse as cursor
    }
    if (bkt == NBK - 1 && tid == 0) row_ptr2[NBK * BK_N] = 2 * E_EDGES;
    __syncthreads();
    for (int i = beg + tid; i < end; i += 256) {
        int2 r = rec[i];
        int d = (r.x >> 17) & (BK_N - 1);
        int g = (r.x >> 24) & 1;
        float c = __int_as_float(r.y) * (g ? invn[d] : invp[d]);
        int p = base[d] + atomicAdd(&cnt[d], 1);        // ds_add_rtn_u32
        rec2[p] = make_int2(r.x & 0x1FFFF, __float_as_int(c));
    }
}

// ---------- MLP stage 1 ----------
__global__ __launch_bounds__(256) void mlp1_kernel(const float* __restrict__ in_feat,
        const float* __restrict__ W1, const float* __restrict__ b1,
        float* __restrict__ x, float* __restrict__ partials) {
    __shared__ float4 sRow4[MB_ROWS * 32];
    __shared__ float  sW1t[32 * 132];
    int tid = threadIdx.x;
    for (int idx = tid; idx < IN_F * HID; idx += 256) {
        int j = idx >> 5, k = idx & 31;
        sW1t[k * 132 + j] = W1[idx];
    }
    int nb = blockIdx.x * MB_ROWS;
    const float4* inf4 = (const float4*)in_feat;
    for (int idx = tid; idx < MB_ROWS * 32; idx += 256) {
        int row = idx >> 5, q = idx & 31;
        int g = nb + row;
        float4 v = (g < N_NODES) ? inf4[(size_t)g * 32 + q] : make_float4(0.f, 0.f, 0.f, 0.f);
        sRow4[row * 32 + (q ^ (row & 31))] = v;
    }
    __syncthreads();
    int rt = tid & 31, kt = tid >> 5;
    int k0 = kt * 4;
    float acc[2][4] = {{0.f}};
    const float4* w0p = (const float4*)&sW1t[(k0 + 0) * 132];
    const float4* w1p = (const float4*)&sW1t[(k0 + 1) * 132];
    const float4* w2p = (const float4*)&sW1t[(k0 + 2) * 132];
    const float4* w3p = (const float4*)&sW1t[(k0 + 3) * 132];
    #pragma unroll 4
    for (int jq = 0; jq < 32; ++jq) {
        int pq = jq ^ rt;
        float4 a0 = sRow4[rt * 32 + pq];
        float4 a1 = sRow4[(rt + 32) * 32 + pq];
        float4 w0 = w0p[jq], w1 = w1p[jq], w2 = w2p[jq], w3 = w3p[jq];
        acc[0][0] += a0.x*w0.x + a0.y*w0.y + a0.z*w0.z + a0.w*w0.w;
        acc[0][1] += a0.x*w1.x + a0.y*w1.y + a0.z*w1.z + a0.w*w1.w;
        acc[0][2] += a0.x*w2.x + a0.y*w2.y + a0.z*w2.z + a0.w*w2.w;
        acc[0][3] += a0.x*w3.x + a0.y*w3.y + a0.z*w3.z + a0.w*w3.w;
        acc[1][0] += a1.x*w0.x + a1.y*w0.y + a1.z*w0.z + a1.w*w0.w;
        acc[1][1] += a1.x*w1.x + a1.y*w1.y + a1.z*w1.z + a1.w*w1.w;
        acc[1][2] += a1.x*w2.x + a1.y*w2.y + a1.z*w2.z + a1.w*w2.w;
        acc[1][3] += a1.x*w3.x + a1.y*w3.y + a1.z*w3.z + a1.w*w3.w;
    }
    float bb[4] = { b1[k0], b1[k0 + 1], b1[k0 + 2], b1[k0 + 3] };
    float s[4] = {0.f, 0.f, 0.f, 0.f}, ss[4] = {0.f, 0.f, 0.f, 0.f};
    #pragma unroll
    for (int i = 0; i < 2; ++i) {
        int row = nb + rt + 32 * i;
        if (row < N_NODES) {
            float4 o;
            o.x = acc[i][0] + bb[0];
            o.y = acc[i][1] + bb[1];
            o.z = acc[i][2] + bb[2];
            o.w = acc[i][3] + bb[3];
            *(float4*)&x[(size_t)row * HID + k0] = o;
            s[0] += o.x; ss[0] += o.x * o.x;
            s[1] += o.y; ss[1] += o.y * o.y;
            s[2] += o.z; ss[2] += o.z * o.z;
            s[3] += o.w; ss[3] += o.w * o.w;
        }
    }
    for (int off = 16; off; off >>= 1) {
        #pragma unroll
        for (int c = 0; c < 4; ++c) {
            s[c]  += __shfl_down(s[c],  off, 32);
            ss[c] += __shfl_down(ss[c], off, 32);
        }
    }
    if (rt == 0) {
        float* pb = partials + (size_t)blockIdx.x * 64;
        #pragma unroll
        for (int c = 0; c < 4; ++c) {
            pb[k0 + c]      = s[c];
            pb[32 + k0 + c] = ss[c];
        }
    }
}

// ---------- reduce partials -> BN scale/shift ----------
__global__ __launch_bounds__(256) void bnparam_kernel(const float* __restrict__ partials,
        const float* __restrict__ gamma, const float* __restrict__ beta, float* __restrict__ params) {
    __shared__ float red[4][64];
    int t = threadIdx.x;
    int col = t & 63, ch = t >> 6;
    float sum = 0.f;
    for (int g = ch; g < MB_BLOCKS; g += 4) sum += partials[(size_t)g * 64 + col];
    red[ch][col] = sum;
    __syncthreads();
    if (t < 64) red[0][t] = red[0][t] + red[1][t] + red[2][t] + red[3][t];
    __syncthreads();
    if (t < HID) {
        float mu  = red[0][t] * (1.0f / (float)N_NODES);
        float var = red[0][t + 32] * (1.0f / (float)N_NODES) - mu * mu;
        float sg = gamma[t] * rsqrtf(var + 1e-5f);
        params[t]       = sg;
        params[HID + t] = beta[t] - mu * sg;
    }
}

// ---------- MLP stage 2: ori_h (fp32) + initial h (fp16) ----------
__global__ __launch_bounds__(256) void mlp2_kernel(const float* __restrict__ x,
        const float* __restrict__ params, const float* __restrict__ W2,
        const float* __restrict__ b2, float* __restrict__ ori_h, __half* __restrict__ h16) {
    __shared__ float sW2[HID * HID];
    __shared__ float sXn[8][HID];
    int tid = threadIdx.x;
    for (int i = tid; i < HID * HID; i += 256) sW2[i] = W2[i];
    int nb = blockIdx.x * 8;
    int k = tid & 31, r = tid >> 5;
    float v = x[(size_t)(nb + r) * HID + k];
    v = fmaxf(fmaf(v, params[k], params[HID + k]), 0.f);
    sXn[r][k] = v;
    __syncthreads();
    float acc = b2[k];
    #pragma unroll
    for (int j = 0; j < HID; ++j) acc = fmaf(sXn[r][j], sW2[j * HID + k], acc);
    int o = (nb + r) * HID + k;
    ori_h[o] = acc;
    h16[o] = __float2half(acc);
}

// ---------- propagation: 2 edge-slots x 16 lanes per node, half2 loads ----------
__global__ __launch_bounds__(256) void gather_kernel(const int* __restrict__ row_ptr,
        const int2* __restrict__ rec, const __half2* __restrict__ h2,
        const float2* __restrict__ ori2, __half2* __restrict__ hn2, float2* __restrict__ out2) {
    int tid = threadIdx.x;
    int node = blockIdx.x * 8 + (tid >> 5);
    int lane = tid & 31;
    int slot = lane >> 4;              // 0 or 1: even/odd edges
    int q = lane & 15;                 // feature pair (2q, 2q+1)
    int beg = row_ptr[node], end = row_ptr[node + 1];
    float2 a0 = {0.f, 0.f}, a1 = {0.f, 0.f}, a2 = {0.f, 0.f}, a3 = {0.f, 0.f};
    int i = beg;
    for (; i + 8 <= end; i += 8) {
        int2 r0 = rec[i + slot];
        int2 r1 = rec[i + 2 + slot];
        int2 r2 = rec[i + 4 + slot];
        int2 r3 = rec[i + 6 + slot];
        float2 f0 = __half22float2(h2[r0.x * 16 + q]);
        float2 f1 = __half22float2(h2[r1.x * 16 + q]);
        float2 f2 = __half22float2(h2[r2.x * 16 + q]);
        float2 f3 = __half22float2(h2[r3.x * 16 + q]);
        float c0 = __int_as_float(r0.y), c1 = __int_as_float(r1.y);
        float c2 = __int_as_float(r2.y), c3 = __int_as_float(r3.y);
        a0.x = fmaf(c0, f0.x, a0.x); a0.y = fmaf(c0, f0.y, a0.y);
        a1.x = fmaf(c1, f1.x, a1.x); a1.y = fmaf(c1, f1.y, a1.y);
        a2.x = fmaf(c2, f2.x, a2.x); a2.y = fmaf(c2, f2.y, a2.y);
        a3.x = fmaf(c3, f3.x, a3.x); a3.y = fmaf(c3, f3.y, a3.y);
    }
    for (; i + 2 <= end; i += 2) {
        int2 r = rec[i + slot];
        float2 f = __half22float2(h2[r.x * 16 + q]);
        float c = __int_as_float(r.y);
        a0.x = fmaf(c, f.x, a0.x); a0.y = fmaf(c, f.y, a0.y);
    }
    if (i < end && slot == 0) {        // last odd edge
        int2 r = rec[i];
        float2 f = __half22float2(h2[r.x * 16 + q]);
        float c = __int_as_float(r.y);
        a0.x = fmaf(c, f.x, a0.x); a0.y = fmaf(c, f.y, a0.y);
    }
    float sx = (a0.x + a1.x) + (a2.x + a3.x);
    float sy = (a0.y + a1.y) + (a2.y + a3.y);
    sx += __shfl_down(sx, 16, 32);     // combine slot1 into slot0
    sy += __shfl_down(sy, 16, 32);
    if (slot == 0) {
        float2 o = ori2[node * 16 + q];
        float rx = o.x + sx, ry = o.y + sy;
        if (out2) out2[node * 16 + q] = make_float2(rx, ry);
        else hn2[node * 16 + q] = __floats2half2_rn(rx, ry);
    }
}

extern "C" void kernel_launch(void* const* d_in, const int* in_sizes, int n_in,
                              void* d_out, int out_size, void* d_ws, size_t ws_size,
                              hipStream_t stream) {
    const float* in_feat = (const float*)d_in[0];
    const float* W1    = (const float*)d_in[1];
    const float* b1    = (const float*)d_in[2];
    const float* gamma = (const float*)d_in[3];
    const float* beta  = (const float*)d_in[4];
    const float* W2    = (const float*)d_in[5];
    const float* b2    = (const float*)d_in[6];
    const int* src  = (const int*)d_in[7];
    const int* dst  = (const int*)d_in[8];
    const int* nsrc = (const int*)d_in[9];
    const int* ndst = (const int*)d_in[10];
    float* out = (float*)d_out;

    // ---- workspace layout ----
    float* ws      = (float*)d_ws;
    float* x       = ws;                                   // N*32 (counts overlay pre-mlp1)
    float* ori_h   = x + (size_t)N_NODES * HID;            // N*32
    float* invs    = ori_h + (size_t)N_NODES * HID;        // 2*N (out-deg p/n)
    float* params  = invs + 2 * (size_t)N_NODES;           // 64
    float* partials= params + 2 * HID;                     // MB_BLOCKS*64
    int*   degs    = (int*)(partials + (size_t)MB_BLOCKS * 64);  // 2*N
    int*   offs    = degs + 2 * N_NODES;                   // L2S+1
    int*   blockSums = offs + L2S + 2;                     // 512
    int*   blockOff  = blockSums + 512;                    // 512
    int*   row_ptr2  = blockOff + 512;                     // NBK*128+1
    __half* h16A   = (__half*)(row_ptr2 + NBK * BK_N + 2); // N*32 fp16
    __half* h16B   = h16A + (size_t)N_NODES * HID;
    uintptr_t rp  = (uintptr_t)(h16B + (size_t)N_NODES * HID);
    rp = (rp + 15) & ~(uintptr_t)15;
    int2*  rec    = (int2*)rp;                             // 2*E records (bucket-major)
    int*   counts = (int*)x;                               // L2S ints; dead before mlp1
    int2*  rec2   = (int2*)in_feat;                        // 51.2 MB, reused after mlp1

    hipMemsetAsync(degs, 0, 2 * (size_t)N_NODES * sizeof(int), stream);

    hist_kernel<<<NWIN * 2 * HS, 256, 0, stream>>>(src, nsrc, degs);
    inv_sqrt_kernel<<<(2 * N_NODES + 255) / 256, 256, 0, stream>>>(degs, invs, 2 * N_NODES);

    countA_kernel<<<FB, 256, 0, stream>>>(dst, ndst, counts);
    scanA2_kernel<<<SCB2, 1024, 0, stream>>>(counts, offs, blockSums);
    scanB2_kernel<<<1, 512, 0, stream>>>(blockSums, blockOff);
    scanC2_kernel<<<SCB2, 1024, 0, stream>>>(offs, blockOff);
    fillA2_kernel<<<FB, 256, 0, stream>>>(src, dst, nsrc, ndst, invs, offs, rec);

    mlp1_kernel<<<MB_BLOCKS, 256, 0, stream>>>(in_feat, W1, b1, x, partials);
    bnparam_kernel<<<1, 256, 0, stream>>>(partials, gamma, beta, params);
    mlp2_kernel<<<N_NODES / 8, 256, 0, stream>>>(x, params, W2, b2, ori_h, h16A);

    // reorder after mlp1 (in_feat dead): node-major CSR + inv_in folded into coef
    reorder_kernel<<<NBK, 256, 0, stream>>>(offs, rec, rec2, row_ptr2);

    const __half* h = h16A;
    for (int it = 0; it < PROP; ++it) {
        __half* hn16 = (it & 1) ? h16A : h16B;
        float* o32 = (it == PROP - 1) ? out : nullptr;
        gather_kernel<<<N_NODES / 8, 256, 0, stream>>>(row_ptr2, rec2,
                (const __half2*)h, (const float2*)ori_h, (__half2*)hn16, (float2*)o32);
        h = hn16;
    }
}